// Round 9
// baseline (415.674 us; speedup 1.0000x reference)
//
#include <hip/hip_runtime.h>

#define DIM 16
#define SEQ 2048
#define CHUNK 64             // keys per chunk
#define NPAIR (CHUNK / 2)    // key pairs per chunk
#define NCHUNK 32            // SEQ / CHUNK
#define RPT 4                // query rows per thread

typedef float v2f __attribute__((ext_vector_type(2)));
typedef float v4f __attribute__((ext_vector_type(4)));

static __device__ __forceinline__ float fexp2(float x) {
#if __has_builtin(__builtin_amdgcn_exp2f)
    return __builtin_amdgcn_exp2f(x);   // raw v_exp_f32; inputs in [-2.9,2.9]
#else
    return exp2f(x);
#endif
}

// ---------------- quantum circuit primitives (all register-resident) --------

template<int P>
__device__ __forceinline__ void rx_bit(float sr[DIM], float si[DIM], float ch, float sh) {
    constexpr int m = 1 << P;
    #pragma unroll
    for (int i = 0; i < DIM; ++i) {
        if ((i & m) == 0) {
            const int j = i | m;
            float r0 = sr[i], i0 = si[i], r1 = sr[j], i1 = si[j];
            sr[i] = fmaf(ch, r0,  sh * i1);
            si[i] = fmaf(ch, i0, -sh * r1);
            sr[j] = fmaf(ch, r1,  sh * i0);
            si[j] = fmaf(ch, i1, -sh * r0);
        }
    }
}

template<int PC, int PT>
__device__ __forceinline__ void cnot_g(float sr[DIM], float si[DIM]) {
    constexpr int cm = 1 << PC, tm = 1 << PT;
    #pragma unroll
    for (int i = 0; i < DIM; ++i) {
        if ((i & cm) && !(i & tm)) {
            const int j = i | tm;
            float t;
            t = sr[i]; sr[i] = sr[j]; sr[j] = t;
            t = si[i]; si[i] = si[j]; si[j] = t;
        }
    }
}

// Fast embed from |0>: state = tensor product of (cos, -i sin) per qubit.
__device__ __forceinline__ void embed(float sr[DIM], float si[DIM], float4 a) {
    float c0, s0, c1, s1, c2, s2, c3, s3;
    __sincosf(0.5f * a.x, &s0, &c0);   // wire 0 -> bit 3
    __sincosf(0.5f * a.y, &s1, &c1);   // wire 1 -> bit 2
    __sincosf(0.5f * a.z, &s2, &c2);   // wire 2 -> bit 1
    __sincosf(0.5f * a.w, &s3, &c3);   // wire 3 -> bit 0
    float A[4] = {c0 * c1, c0 * s1, s0 * c1, s0 * s1};   // bits (b3,b2)
    float B[4] = {c2 * c3, c2 * s3, s2 * c3, s2 * s3};   // bits (b1,b0)
    #pragma unroll
    for (int idx = 0; idx < DIM; ++idx) {
        const float p = A[idx >> 2] * B[idx & 3];
        const int m = __builtin_popcount(idx) & 3;
        sr[idx] = (m == 0) ? p : (m == 2) ? -p : 0.f;
        si[idx] = (m == 1) ? -p : (m == 3) ? p : 0.f;
    }
}

__device__ __forceinline__ void layer(float sr[DIM], float si[DIM], float4 w) {
    float ch, sh;
    __sincosf(0.5f * w.x, &sh, &ch); rx_bit<3>(sr, si, ch, sh);
    __sincosf(0.5f * w.y, &sh, &ch); rx_bit<2>(sr, si, ch, sh);
    __sincosf(0.5f * w.z, &sh, &ch); rx_bit<1>(sr, si, ch, sh);
    __sincosf(0.5f * w.w, &sh, &ch); rx_bit<0>(sr, si, ch, sh);
    cnot_g<3,2>(sr, si);
    cnot_g<2,1>(sr, si);
    cnot_g<1,0>(sr, si);
    cnot_g<0,3>(sr, si);
}

__device__ __forceinline__ float4 measure(const float sr[DIM], const float si[DIM]) {
    float e0 = 0.f, e1 = 0.f, e2 = 0.f, e3 = 0.f;
    #pragma unroll
    for (int i = 0; i < DIM; ++i) {
        float p = fmaf(sr[i], sr[i], si[i] * si[i]);
        e0 += (i & 8) ? -p : p;
        e1 += (i & 4) ? -p : p;
        e2 += (i & 2) ? -p : p;
        e3 += (i & 1) ? -p : p;
    }
    return make_float4(e0, e1, e2, e3);
}

// ---------------- kernel 1: Q,K,V circuits (split over blockIdx.y) ---------
// K and V stored PAIR-TRANSPOSED in global:
//   per key pair p: [kx0,kx1, ky0,ky1, kz0,kz1, kw0,kw1]  (8 floats)

__global__ __launch_bounds__(256) void qkv_kernel(
        const float* __restrict__ x,
        const float* __restrict__ wQp, const float* __restrict__ wKp,
        const float* __restrict__ wVp,
        float4* __restrict__ Q, float* __restrict__ Kt, float* __restrict__ Vt) {
    const int i = blockIdx.x * 256 + threadIdx.x;
    const int which = blockIdx.y;          // 0=Q, 1=K, 2=V
    const float4 xv = ((const float4*)x)[i];
    const float* wp = (which == 0) ? wQp : (which == 1) ? wKp : wVp;
    const float4 w = *(const float4*)wp;

    float sr[DIM], si[DIM];
    embed(sr, si, xv);
    layer(sr, si, w);
    const float4 r = measure(sr, si);

    if (which == 0) {
        Q[i] = r;
    } else {
        const int bb = i >> 11, rr = i & (SEQ - 1);
        const int p = rr >> 1, h = rr & 1;
        float* base = ((which == 1) ? Kt : Vt)
                      + ((size_t)bb * (SEQ / 2) + p) * 8 + h;
        base[0] = r.x; base[2] = r.y; base[4] = r.z; base[6] = r.w;
    }
}

// ---------------- kernel 2: attention partials -----------------------------
// Grid (64 row-groups of 1024 rows, 32 chunks) = 2048 blocks = 8/CU.
// LDS-read demand per CU is 41/RPT us independent of NCHUNK, so NCHUNK is a
// free occupancy knob: 32 chunks doubles blocks/CU vs R8 at the same LDS
// cost. K through the scalar path (uniform v4f loads -> SGPRs feeding
// v_pk_fma); V in LDS (1 KB); q pre-packed v2f. launch_bounds(256,6) caps
// VGPR ~85 for ~6 waves/SIMD.

__global__ __launch_bounds__(256, 6) void attn_partial(
        const v4f* __restrict__ Q, const float* __restrict__ Kt,
        const float* __restrict__ Vt,
        float* __restrict__ pden, v4f* __restrict__ pctx, int n) {
    __shared__ v4f vs[2 * NPAIR];   // 1 KB

    const int rg = blockIdx.x;          // row-group (1024 rows)
    const int c  = blockIdx.y;          // key chunk
    const int b  = rg >> 1;             // 2 row-groups per batch

    // ---- stage V chunk (pair-transposed, straight copy) ----
    const v4f* Vtc = (const v4f*)(Vt + ((size_t)b * (SEQ / 2) + c * NPAIR) * 8);
    if (threadIdx.x < 2 * NPAIR)
        vs[threadIdx.x] = Vtc[threadIdx.x];
    __syncthreads();

    // fold 0.5 (1/sqrt(E)) * log2(e): loop uses raw exp2
    const float SC = 0.72134752044f;
    const int row0 = rg * (256 * RPT) + threadIdx.x;

    v2f qx[RPT], qy[RPT], qz[RPT], qw[RPT];
    #pragma unroll
    for (int j = 0; j < RPT; ++j) {
        const v4f q = __builtin_nontemporal_load(Q + (row0 + j * 256));
        qx[j] = (v2f){q.x * SC, q.x * SC};
        qy[j] = (v2f){q.y * SC, q.y * SC};
        qz[j] = (v2f){q.z * SC, q.z * SC};
        qw[j] = (v2f){q.w * SC, q.w * SC};
    }

    v2f den[RPT], ax[RPT], ay[RPT], az[RPT], aw[RPT];
    #pragma unroll
    for (int j = 0; j < RPT; ++j) {
        den[j] = (v2f){0.f, 0.f};
        ax[j] = den[j]; ay[j] = den[j]; az[j] = den[j]; aw[j] = den[j];
    }

    // K chunk base: uniform address -> scalar (s_load) path
    const v4f* Ktc = (const v4f*)(Kt + ((size_t)b * (SEQ / 2) + c * NPAIR) * 8);

    #pragma unroll 4
    for (int p = 0; p < NPAIR; ++p) {
        const v4f kAB = Ktc[2 * p + 0];  // (kx0,kx1 | ky0,ky1) uniform
        const v4f kCD = Ktc[2 * p + 1];  // (kz0,kz1 | kw0,kw1) uniform
        const v2f kx = kAB.xy, ky = kAB.zw, kz = kCD.xy, kw = kCD.zw;
        const v4f vA = vs[2 * p + 0];    // (V0x,V1x | V0y,V1y)
        const v4f vB = vs[2 * p + 1];    // (V0z,V1z | V0w,V1w)
        const v2f vx = vA.xy, vy = vA.zw, vz = vB.xy, vw = vB.zw;
        #pragma unroll
        for (int j = 0; j < RPT; ++j) {
            v2f s = __builtin_elementwise_fma(qy[j], ky, qx[j] * kx);
            s     = __builtin_elementwise_fma(qz[j], kz, s);
            s     = __builtin_elementwise_fma(qw[j], kw, s);
            const v2f e = (v2f){fexp2(s.x), fexp2(s.y)};   // 2 keys
            den[j] += e;
            ax[j] = __builtin_elementwise_fma(e, vx, ax[j]);
            ay[j] = __builtin_elementwise_fma(e, vy, ay[j]);
            az[j] = __builtin_elementwise_fma(e, vz, az[j]);
            aw[j] = __builtin_elementwise_fma(e, vw, aw[j]);
        }
    }

    #pragma unroll
    for (int j = 0; j < RPT; ++j) {
        const int row = row0 + j * 256;
        __builtin_nontemporal_store(den[j].x + den[j].y, pden + ((size_t)c * n + row));
        const v4f ct = (v4f){ax[j].x + ax[j].y, ay[j].x + ay[j].y,
                             az[j].x + az[j].y, aw[j].x + aw[j].y};
        __builtin_nontemporal_store(ct, pctx + ((size_t)c * n + row));
    }
}

// ---------------- kernel 3: combine partials + final circuit ---------------

__global__ __launch_bounds__(256) void combine_kernel(
        const float* __restrict__ pden, const v4f* __restrict__ pctx,
        const float* __restrict__ wCp, float4* __restrict__ out, int n) {
    const int row = blockIdx.x * 256 + threadIdx.x;

    float d = 0.f;
    float c0 = 0.f, c1 = 0.f, c2 = 0.f, c3 = 0.f;
    #pragma unroll 8
    for (int c = 0; c < NCHUNK; ++c) {
        d += __builtin_nontemporal_load(pden + ((size_t)c * n + row));
        const v4f p = __builtin_nontemporal_load(pctx + ((size_t)c * n + row));
        c0 += p.x; c1 += p.y; c2 += p.z; c3 += p.w;
    }
    const float inv = 1.0f / d;
    const float4 ctx = make_float4(c0 * inv, c1 * inv, c2 * inv, c3 * inv);

    const float4 wC = *(const float4*)wCp;
    float sr[DIM], si[DIM];
    embed(sr, si, ctx);
    layer(sr, si, wC);
    out[row] = measure(sr, si);
}

// ---------------- launch ---------------------------------------------------

extern "C" void kernel_launch(void* const* d_in, const int* in_sizes, int n_in,
                              void* d_out, int out_size, void* d_ws, size_t ws_size,
                              hipStream_t stream) {
    const float* x  = (const float*)d_in[0];
    const float* wQ = (const float*)d_in[1];
    const float* wK = (const float*)d_in[2];
    const float* wV = (const float*)d_in[3];
    const float* wC = (const float*)d_in[4];

    const int n = in_sizes[0] / 4;              // B*S = 65536 rows
    float4* Q    = (float4*)d_ws;               // n float4          = 1 MB
    float*  Kt   = (float*)(Q + n);             // 4n float          = 1 MB
    float*  Vt   = Kt + 4 * n;                  // 4n float          = 1 MB
    v4f*   pctx  = (v4f*)(Vt + 4 * n);          // NCHUNK*n v4f      = 33.6 MB
    float* pden  = (float*)(pctx + (size_t)NCHUNK * n); // NCHUNK*n  = 8.4 MB

    dim3 qgrid(n / 256, 3);
    qkv_kernel<<<qgrid, 256, 0, stream>>>(x, wQ, wK, wV, Q, Kt, Vt);

    dim3 agrid(n / (256 * RPT), NCHUNK);        // (64, 32) = 2048 blocks
    attn_partial<<<agrid, 256, 0, stream>>>((const v4f*)Q, Kt, Vt,
                                            pden, pctx, n);

    combine_kernel<<<n / 256, 256, 0, stream>>>(pden, pctx, wC, (float4*)d_out, n);
}

// Round 10
// 106.011 us; speedup vs baseline: 3.9211x; 3.9211x over previous
//
#include <hip/hip_runtime.h>

#define DIM 16
#define SEQ 2048
#define CHUNK 64             // keys per chunk
#define NPAIR (CHUNK / 2)    // key pairs per chunk
#define NCHUNK 32            // SEQ / CHUNK
#define RPT 4                // query rows per thread

typedef float v2f __attribute__((ext_vector_type(2)));
typedef float v4f __attribute__((ext_vector_type(4)));

static __device__ __forceinline__ float fexp2(float x) {
#if __has_builtin(__builtin_amdgcn_exp2f)
    return __builtin_amdgcn_exp2f(x);   // raw v_exp_f32; inputs in [-2.9,2.9]
#else
    return exp2f(x);
#endif
}

// ---------------- quantum circuit primitives (all register-resident) --------

template<int P>
__device__ __forceinline__ void rx_bit(float sr[DIM], float si[DIM], float ch, float sh) {
    constexpr int m = 1 << P;
    #pragma unroll
    for (int i = 0; i < DIM; ++i) {
        if ((i & m) == 0) {
            const int j = i | m;
            float r0 = sr[i], i0 = si[i], r1 = sr[j], i1 = si[j];
            sr[i] = fmaf(ch, r0,  sh * i1);
            si[i] = fmaf(ch, i0, -sh * r1);
            sr[j] = fmaf(ch, r1,  sh * i0);
            si[j] = fmaf(ch, i1, -sh * r0);
        }
    }
}

template<int PC, int PT>
__device__ __forceinline__ void cnot_g(float sr[DIM], float si[DIM]) {
    constexpr int cm = 1 << PC, tm = 1 << PT;
    #pragma unroll
    for (int i = 0; i < DIM; ++i) {
        if ((i & cm) && !(i & tm)) {
            const int j = i | tm;
            float t;
            t = sr[i]; sr[i] = sr[j]; sr[j] = t;
            t = si[i]; si[i] = si[j]; si[j] = t;
        }
    }
}

// Fast embed from |0>: state = tensor product of (cos, -i sin) per qubit.
__device__ __forceinline__ void embed(float sr[DIM], float si[DIM], float4 a) {
    float c0, s0, c1, s1, c2, s2, c3, s3;
    __sincosf(0.5f * a.x, &s0, &c0);   // wire 0 -> bit 3
    __sincosf(0.5f * a.y, &s1, &c1);   // wire 1 -> bit 2
    __sincosf(0.5f * a.z, &s2, &c2);   // wire 2 -> bit 1
    __sincosf(0.5f * a.w, &s3, &c3);   // wire 3 -> bit 0
    float A[4] = {c0 * c1, c0 * s1, s0 * c1, s0 * s1};   // bits (b3,b2)
    float B[4] = {c2 * c3, c2 * s3, s2 * c3, s2 * s3};   // bits (b1,b0)
    #pragma unroll
    for (int idx = 0; idx < DIM; ++idx) {
        const float p = A[idx >> 2] * B[idx & 3];
        const int m = __builtin_popcount(idx) & 3;
        sr[idx] = (m == 0) ? p : (m == 2) ? -p : 0.f;
        si[idx] = (m == 1) ? -p : (m == 3) ? p : 0.f;
    }
}

__device__ __forceinline__ void layer(float sr[DIM], float si[DIM], float4 w) {
    float ch, sh;
    __sincosf(0.5f * w.x, &sh, &ch); rx_bit<3>(sr, si, ch, sh);
    __sincosf(0.5f * w.y, &sh, &ch); rx_bit<2>(sr, si, ch, sh);
    __sincosf(0.5f * w.z, &sh, &ch); rx_bit<1>(sr, si, ch, sh);
    __sincosf(0.5f * w.w, &sh, &ch); rx_bit<0>(sr, si, ch, sh);
    cnot_g<3,2>(sr, si);
    cnot_g<2,1>(sr, si);
    cnot_g<1,0>(sr, si);
    cnot_g<0,3>(sr, si);
}

__device__ __forceinline__ float4 measure(const float sr[DIM], const float si[DIM]) {
    float e0 = 0.f, e1 = 0.f, e2 = 0.f, e3 = 0.f;
    #pragma unroll
    for (int i = 0; i < DIM; ++i) {
        float p = fmaf(sr[i], sr[i], si[i] * si[i]);
        e0 += (i & 8) ? -p : p;
        e1 += (i & 4) ? -p : p;
        e2 += (i & 2) ? -p : p;
        e3 += (i & 1) ? -p : p;
    }
    return make_float4(e0, e1, e2, e3);
}

// ---------------- kernel 1: Q,K,V circuits (split over blockIdx.y) ---------
// K and V stored PAIR-TRANSPOSED in global:
//   per key pair p: [kx0,kx1, ky0,ky1, kz0,kz1, kw0,kw1]  (8 floats)

__global__ __launch_bounds__(256) void qkv_kernel(
        const float* __restrict__ x,
        const float* __restrict__ wQp, const float* __restrict__ wKp,
        const float* __restrict__ wVp,
        float4* __restrict__ Q, float* __restrict__ Kt, float* __restrict__ Vt) {
    const int i = blockIdx.x * 256 + threadIdx.x;
    const int which = blockIdx.y;          // 0=Q, 1=K, 2=V
    const float4 xv = ((const float4*)x)[i];
    const float* wp = (which == 0) ? wQp : (which == 1) ? wKp : wVp;
    const float4 w = *(const float4*)wp;

    float sr[DIM], si[DIM];
    embed(sr, si, xv);
    layer(sr, si, w);
    const float4 r = measure(sr, si);

    if (which == 0) {
        Q[i] = r;
    } else {
        const int bb = i >> 11, rr = i & (SEQ - 1);
        const int p = rr >> 1, h = rr & 1;
        float* base = ((which == 1) ? Kt : Vt)
                      + ((size_t)bb * (SEQ / 2) + p) * 8 + h;
        base[0] = r.x; base[2] = r.y; base[4] = r.z; base[6] = r.w;
    }
}

// ---------------- kernel 2: attention partials -----------------------------
// Grid (64 row-groups of 1024 rows, 32 chunks) = 2048 blocks = 8/CU.
// LDS-read demand per CU is 41/RPT us independent of NCHUNK -> NCHUNK is a
// free occupancy knob. K via uniform loads (scalar path); V in LDS (1 KB);
// q pre-packed v2f. launch_bounds(256,4): R9's (256,6) spilled the 72+ VGPR
// live set to scratch (1.4 GB HBM traffic, 8x regression) — do NOT tighten.
// Q loads are cached (32x reuse across chunk-blocks); partial stores NT.

__global__ __launch_bounds__(256, 4) void attn_partial(
        const v4f* __restrict__ Q, const float* __restrict__ Kt,
        const float* __restrict__ Vt,
        float* __restrict__ pden, v4f* __restrict__ pctx, int n) {
    __shared__ v4f vs[2 * NPAIR];   // 1 KB

    const int rg = blockIdx.x;          // row-group (1024 rows)
    const int c  = blockIdx.y;          // key chunk
    const int b  = rg >> 1;             // 2 row-groups per batch

    // ---- stage V chunk (pair-transposed, straight copy) ----
    const v4f* Vtc = (const v4f*)(Vt + ((size_t)b * (SEQ / 2) + c * NPAIR) * 8);
    if (threadIdx.x < 2 * NPAIR)
        vs[threadIdx.x] = Vtc[threadIdx.x];
    __syncthreads();

    // fold 0.5 (1/sqrt(E)) * log2(e): loop uses raw exp2
    const float SC = 0.72134752044f;
    const int row0 = rg * (256 * RPT) + threadIdx.x;

    v2f qx[RPT], qy[RPT], qz[RPT], qw[RPT];
    #pragma unroll
    for (int j = 0; j < RPT; ++j) {
        const v4f q = Q[row0 + j * 256];     // L2-cached: 32x reuse
        qx[j] = (v2f){q.x * SC, q.x * SC};
        qy[j] = (v2f){q.y * SC, q.y * SC};
        qz[j] = (v2f){q.z * SC, q.z * SC};
        qw[j] = (v2f){q.w * SC, q.w * SC};
    }

    v2f den[RPT], ax[RPT], ay[RPT], az[RPT], aw[RPT];
    #pragma unroll
    for (int j = 0; j < RPT; ++j) {
        den[j] = (v2f){0.f, 0.f};
        ax[j] = den[j]; ay[j] = den[j]; az[j] = den[j]; aw[j] = den[j];
    }

    // K chunk base: uniform address -> scalar (s_load) path
    const v4f* Ktc = (const v4f*)(Kt + ((size_t)b * (SEQ / 2) + c * NPAIR) * 8);

    #pragma unroll 4
    for (int p = 0; p < NPAIR; ++p) {
        const v4f kAB = Ktc[2 * p + 0];  // (kx0,kx1 | ky0,ky1) uniform
        const v4f kCD = Ktc[2 * p + 1];  // (kz0,kz1 | kw0,kw1) uniform
        const v2f kx = kAB.xy, ky = kAB.zw, kz = kCD.xy, kw = kCD.zw;
        const v4f vA = vs[2 * p + 0];    // (V0x,V1x | V0y,V1y)
        const v4f vB = vs[2 * p + 1];    // (V0z,V1z | V0w,V1w)
        const v2f vx = vA.xy, vy = vA.zw, vz = vB.xy, vw = vB.zw;
        #pragma unroll
        for (int j = 0; j < RPT; ++j) {
            v2f s = __builtin_elementwise_fma(qy[j], ky, qx[j] * kx);
            s     = __builtin_elementwise_fma(qz[j], kz, s);
            s     = __builtin_elementwise_fma(qw[j], kw, s);
            const v2f e = (v2f){fexp2(s.x), fexp2(s.y)};   // 2 keys
            den[j] += e;
            ax[j] = __builtin_elementwise_fma(e, vx, ax[j]);
            ay[j] = __builtin_elementwise_fma(e, vy, ay[j]);
            az[j] = __builtin_elementwise_fma(e, vz, az[j]);
            aw[j] = __builtin_elementwise_fma(e, vw, aw[j]);
        }
    }

    #pragma unroll
    for (int j = 0; j < RPT; ++j) {
        const int row = row0 + j * 256;
        __builtin_nontemporal_store(den[j].x + den[j].y, pden + ((size_t)c * n + row));
        const v4f ct = (v4f){ax[j].x + ax[j].y, ay[j].x + ay[j].y,
                             az[j].x + az[j].y, aw[j].x + aw[j].y};
        __builtin_nontemporal_store(ct, pctx + ((size_t)c * n + row));
    }
}

// ---------------- kernel 3: combine partials + final circuit ---------------

__global__ __launch_bounds__(256) void combine_kernel(
        const float* __restrict__ pden, const v4f* __restrict__ pctx,
        const float* __restrict__ wCp, float4* __restrict__ out, int n) {
    const int row = blockIdx.x * 256 + threadIdx.x;

    float d = 0.f;
    float c0 = 0.f, c1 = 0.f, c2 = 0.f, c3 = 0.f;
    #pragma unroll 8
    for (int c = 0; c < NCHUNK; ++c) {
        d += __builtin_nontemporal_load(pden + ((size_t)c * n + row));
        const v4f p = __builtin_nontemporal_load(pctx + ((size_t)c * n + row));
        c0 += p.x; c1 += p.y; c2 += p.z; c3 += p.w;
    }
    const float inv = 1.0f / d;
    const float4 ctx = make_float4(c0 * inv, c1 * inv, c2 * inv, c3 * inv);

    const float4 wC = *(const float4*)wCp;
    float sr[DIM], si[DIM];
    embed(sr, si, ctx);
    layer(sr, si, wC);
    out[row] = measure(sr, si);
}

// ---------------- launch ---------------------------------------------------

extern "C" void kernel_launch(void* const* d_in, const int* in_sizes, int n_in,
                              void* d_out, int out_size, void* d_ws, size_t ws_size,
                              hipStream_t stream) {
    const float* x  = (const float*)d_in[0];
    const float* wQ = (const float*)d_in[1];
    const float* wK = (const float*)d_in[2];
    const float* wV = (const float*)d_in[3];
    const float* wC = (const float*)d_in[4];

    const int n = in_sizes[0] / 4;              // B*S = 65536 rows
    float4* Q    = (float4*)d_ws;               // n float4          = 1 MB
    float*  Kt   = (float*)(Q + n);             // 4n float          = 1 MB
    float*  Vt   = Kt + 4 * n;                  // 4n float          = 1 MB
    v4f*   pctx  = (v4f*)(Vt + 4 * n);          // NCHUNK*n v4f      = 33.6 MB
    float* pden  = (float*)(pctx + (size_t)NCHUNK * n); // NCHUNK*n  = 8.4 MB

    dim3 qgrid(n / 256, 3);
    qkv_kernel<<<qgrid, 256, 0, stream>>>(x, wQ, wK, wV, Q, Kt, Vt);

    dim3 agrid(n / (256 * RPT), NCHUNK);        // (64, 32) = 2048 blocks
    attn_partial<<<agrid, 256, 0, stream>>>((const v4f*)Q, Kt, Vt,
                                            pden, pctx, n);

    combine_kernel<<<n / 256, 256, 0, stream>>>(pden, pctx, wC, (float4*)d_out, n);
}

// Round 11
// 104.482 us; speedup vs baseline: 3.9784x; 1.0146x over previous
//
#include <hip/hip_runtime.h>

#define DIM 16
#define SEQ 2048
#define CHUNK 128            // keys per chunk
#define NPAIR (CHUNK / 2)    // key pairs per chunk
#define NCHUNK 16            // SEQ / CHUNK
#define RPT 4                // query rows per thread

typedef float v2f __attribute__((ext_vector_type(2)));
typedef float v4f __attribute__((ext_vector_type(4)));

static __device__ __forceinline__ float fexp2(float x) {
#if __has_builtin(__builtin_amdgcn_exp2f)
    return __builtin_amdgcn_exp2f(x);   // raw v_exp_f32; inputs in [-2.9,2.9]
#else
    return exp2f(x);
#endif
}

// ---------------- quantum circuit primitives (all register-resident) --------

template<int P>
__device__ __forceinline__ void rx_bit(float sr[DIM], float si[DIM], float ch, float sh) {
    constexpr int m = 1 << P;
    #pragma unroll
    for (int i = 0; i < DIM; ++i) {
        if ((i & m) == 0) {
            const int j = i | m;
            float r0 = sr[i], i0 = si[i], r1 = sr[j], i1 = si[j];
            sr[i] = fmaf(ch, r0,  sh * i1);
            si[i] = fmaf(ch, i0, -sh * r1);
            sr[j] = fmaf(ch, r1,  sh * i0);
            si[j] = fmaf(ch, i1, -sh * r0);
        }
    }
}

template<int PC, int PT>
__device__ __forceinline__ void cnot_g(float sr[DIM], float si[DIM]) {
    constexpr int cm = 1 << PC, tm = 1 << PT;
    #pragma unroll
    for (int i = 0; i < DIM; ++i) {
        if ((i & cm) && !(i & tm)) {
            const int j = i | tm;
            float t;
            t = sr[i]; sr[i] = sr[j]; sr[j] = t;
            t = si[i]; si[i] = si[j]; si[j] = t;
        }
    }
}

// Fast embed from |0>: state = tensor product of (cos, -i sin) per qubit.
__device__ __forceinline__ void embed(float sr[DIM], float si[DIM], float4 a) {
    float c0, s0, c1, s1, c2, s2, c3, s3;
    __sincosf(0.5f * a.x, &s0, &c0);   // wire 0 -> bit 3
    __sincosf(0.5f * a.y, &s1, &c1);   // wire 1 -> bit 2
    __sincosf(0.5f * a.z, &s2, &c2);   // wire 2 -> bit 1
    __sincosf(0.5f * a.w, &s3, &c3);   // wire 3 -> bit 0
    float A[4] = {c0 * c1, c0 * s1, s0 * c1, s0 * s1};   // bits (b3,b2)
    float B[4] = {c2 * c3, c2 * s3, s2 * c3, s2 * s3};   // bits (b1,b0)
    #pragma unroll
    for (int idx = 0; idx < DIM; ++idx) {
        const float p = A[idx >> 2] * B[idx & 3];
        const int m = __builtin_popcount(idx) & 3;
        sr[idx] = (m == 0) ? p : (m == 2) ? -p : 0.f;
        si[idx] = (m == 1) ? -p : (m == 3) ? p : 0.f;
    }
}

__device__ __forceinline__ void layer(float sr[DIM], float si[DIM], float4 w) {
    float ch, sh;
    __sincosf(0.5f * w.x, &sh, &ch); rx_bit<3>(sr, si, ch, sh);
    __sincosf(0.5f * w.y, &sh, &ch); rx_bit<2>(sr, si, ch, sh);
    __sincosf(0.5f * w.z, &sh, &ch); rx_bit<1>(sr, si, ch, sh);
    __sincosf(0.5f * w.w, &sh, &ch); rx_bit<0>(sr, si, ch, sh);
    cnot_g<3,2>(sr, si);
    cnot_g<2,1>(sr, si);
    cnot_g<1,0>(sr, si);
    cnot_g<0,3>(sr, si);
}

__device__ __forceinline__ float4 measure(const float sr[DIM], const float si[DIM]) {
    float e0 = 0.f, e1 = 0.f, e2 = 0.f, e3 = 0.f;
    #pragma unroll
    for (int i = 0; i < DIM; ++i) {
        float p = fmaf(sr[i], sr[i], si[i] * si[i]);
        e0 += (i & 8) ? -p : p;
        e1 += (i & 4) ? -p : p;
        e2 += (i & 2) ? -p : p;
        e3 += (i & 1) ? -p : p;
    }
    return make_float4(e0, e1, e2, e3);
}

// ---------------- kernel 1: Q,K,V circuits (split over blockIdx.y) ---------
// K,V stored PAIR-INTERLEAVED in one 64 B block per key pair:
//   [kx0,kx1, ky0,ky1, kz0,kz1, kw0,kw1 | vx0,vx1, vy0,vy1, vz0,vz1, vw0,vw1]
// so the attention kernel fetches a whole pair with ONE uniform 64 B
// scalar load (s_load_dwordx16) -> K,V live in SGPRs, never VGPRs/LDS.

__global__ __launch_bounds__(256) void qkv_kernel(
        const float* __restrict__ x,
        const float* __restrict__ wQp, const float* __restrict__ wKp,
        const float* __restrict__ wVp,
        float4* __restrict__ Q, float* __restrict__ KVt) {
    const int i = blockIdx.x * 256 + threadIdx.x;
    const int which = blockIdx.y;          // 0=Q, 1=K, 2=V
    const float4 xv = ((const float4*)x)[i];
    const float* wp = (which == 0) ? wQp : (which == 1) ? wKp : wVp;
    const float4 w = *(const float4*)wp;

    float sr[DIM], si[DIM];
    embed(sr, si, xv);
    layer(sr, si, w);
    const float4 r = measure(sr, si);

    if (which == 0) {
        Q[i] = r;
    } else {
        const int bb = i >> 11, rr = i & (SEQ - 1);
        const int p = rr >> 1, h = rr & 1;
        float* base = KVt + ((size_t)bb * (SEQ / 2) + p) * 16 + h
                      + ((which == 2) ? 8 : 0);
        base[0] = r.x; base[2] = r.y; base[4] = r.z; base[6] = r.w;
    }
}

// ---------------- kernel 2: attention partials -----------------------------
// Grid (64 row-groups of 1024 rows, 16 chunks) = 1024 blocks = 4/CU.
// NO LDS, NO barrier: K,V flow through the scalar path only (uniform 64 B
// loads -> SGPRs; each v_pk_fma reads exactly one SGPR-pair operand, which
// is legal). This unifies all loop waits onto pure-SMEM lgkmcnt — the
// R7-R10 wall was s_load/ds_read sharing lgkmcnt, forcing full drains.
// q pre-packed v2f in VGPRs; acc in VGPRs. ~87 VGPR, no spill at (256,4).

__global__ __launch_bounds__(256, 4) void attn_partial(
        const v4f* __restrict__ Q, const float* __restrict__ KVt,
        float* __restrict__ pden, v4f* __restrict__ pctx, int n) {
    const int rg = blockIdx.x;          // row-group (1024 rows)
    const int c  = blockIdx.y;          // key chunk
    const int b  = rg >> 1;             // 2 row-groups per batch

    // fold 0.5 (1/sqrt(E)) * log2(e): loop uses raw exp2
    const float SC = 0.72134752044f;
    const int row0 = rg * (256 * RPT) + threadIdx.x;

    v2f qx[RPT], qy[RPT], qz[RPT], qw[RPT];
    #pragma unroll
    for (int j = 0; j < RPT; ++j) {
        const v4f q = Q[row0 + j * 256];     // L2-cached: 16x reuse
        qx[j] = (v2f){q.x * SC, q.x * SC};
        qy[j] = (v2f){q.y * SC, q.y * SC};
        qz[j] = (v2f){q.z * SC, q.z * SC};
        qw[j] = (v2f){q.w * SC, q.w * SC};
    }

    v2f den[RPT], ax[RPT], ay[RPT], az[RPT], aw[RPT];
    #pragma unroll
    for (int j = 0; j < RPT; ++j) {
        den[j] = (v2f){0.f, 0.f};
        ax[j] = den[j]; ay[j] = den[j]; az[j] = den[j]; aw[j] = den[j];
    }

    // chunk base: uniform address -> scalar (s_load) path, 64 B per pair
    const v4f* KVc = (const v4f*)(KVt + ((size_t)b * (SEQ / 2) + c * NPAIR) * 16);

    #pragma unroll 2
    for (int p = 0; p < NPAIR; ++p) {
        const v4f kAB = KVc[4 * p + 0];  // (kx0,kx1 | ky0,ky1)  uniform->SGPR
        const v4f kCD = KVc[4 * p + 1];  // (kz0,kz1 | kw0,kw1)
        const v4f vAB = KVc[4 * p + 2];  // (vx0,vx1 | vy0,vy1)
        const v4f vCD = KVc[4 * p + 3];  // (vz0,vz1 | vw0,vw1)
        const v2f kx = kAB.xy, ky = kAB.zw, kz = kCD.xy, kw = kCD.zw;
        const v2f vx = vAB.xy, vy = vAB.zw, vz = vCD.xy, vw = vCD.zw;
        #pragma unroll
        for (int j = 0; j < RPT; ++j) {
            v2f s = __builtin_elementwise_fma(qy[j], ky, qx[j] * kx);
            s     = __builtin_elementwise_fma(qz[j], kz, s);
            s     = __builtin_elementwise_fma(qw[j], kw, s);
            const v2f e = (v2f){fexp2(s.x), fexp2(s.y)};   // 2 keys
            den[j] += e;
            ax[j] = __builtin_elementwise_fma(e, vx, ax[j]);
            ay[j] = __builtin_elementwise_fma(e, vy, ay[j]);
            az[j] = __builtin_elementwise_fma(e, vz, az[j]);
            aw[j] = __builtin_elementwise_fma(e, vw, aw[j]);
        }
    }

    #pragma unroll
    for (int j = 0; j < RPT; ++j) {
        const int row = row0 + j * 256;
        __builtin_nontemporal_store(den[j].x + den[j].y, pden + ((size_t)c * n + row));
        const v4f ct = (v4f){ax[j].x + ax[j].y, ay[j].x + ay[j].y,
                             az[j].x + az[j].y, aw[j].x + aw[j].y};
        __builtin_nontemporal_store(ct, pctx + ((size_t)c * n + row));
    }
}

// ---------------- kernel 3: combine partials + final circuit ---------------

__global__ __launch_bounds__(256) void combine_kernel(
        const float* __restrict__ pden, const v4f* __restrict__ pctx,
        const float* __restrict__ wCp, float4* __restrict__ out, int n) {
    const int row = blockIdx.x * 256 + threadIdx.x;

    float d = 0.f;
    float c0 = 0.f, c1 = 0.f, c2 = 0.f, c3 = 0.f;
    #pragma unroll 8
    for (int c = 0; c < NCHUNK; ++c) {
        d += __builtin_nontemporal_load(pden + ((size_t)c * n + row));
        const v4f p = __builtin_nontemporal_load(pctx + ((size_t)c * n + row));
        c0 += p.x; c1 += p.y; c2 += p.z; c3 += p.w;
    }
    const float inv = 1.0f / d;
    const float4 ctx = make_float4(c0 * inv, c1 * inv, c2 * inv, c3 * inv);

    const float4 wC = *(const float4*)wCp;
    float sr[DIM], si[DIM];
    embed(sr, si, ctx);
    layer(sr, si, wC);
    out[row] = measure(sr, si);
}

// ---------------- launch ---------------------------------------------------

extern "C" void kernel_launch(void* const* d_in, const int* in_sizes, int n_in,
                              void* d_out, int out_size, void* d_ws, size_t ws_size,
                              hipStream_t stream) {
    const float* x  = (const float*)d_in[0];
    const float* wQ = (const float*)d_in[1];
    const float* wK = (const float*)d_in[2];
    const float* wV = (const float*)d_in[3];
    const float* wC = (const float*)d_in[4];

    const int n = in_sizes[0] / 4;              // B*S = 65536 rows
    float4* Q    = (float4*)d_ws;               // n float4          = 1 MB
    float*  KVt  = (float*)(Q + n);             // 8n float          = 2 MB
    v4f*   pctx  = (v4f*)(KVt + 8 * n);         // NCHUNK*n v4f      = 16.8 MB
    float* pden  = (float*)(pctx + (size_t)NCHUNK * n); // NCHUNK*n  = 4.2 MB

    dim3 qgrid(n / 256, 3);
    qkv_kernel<<<qgrid, 256, 0, stream>>>(x, wQ, wK, wV, Q, KVt);

    dim3 agrid(n / (256 * RPT), NCHUNK);        // (64, 16) = 1024 blocks
    attn_partial<<<agrid, 256, 0, stream>>>((const v4f*)Q, KVt,
                                            pden, pctx, n);

    combine_kernel<<<n / 256, 256, 0, stream>>>(pden, pctx, wC, (float4*)d_out, n);
}